// Round 5
// baseline (487.445 us; speedup 1.0000x reference)
//
#include <hip/hip_runtime.h>
#include <stdint.h>

// ---------------------------------------------------------------------------
// Fastformer fused pipeline, MI355X gfx950.  Round 5:
//  - gemm: seg-major LDS (conflict-free b128 fragment reads, DMA-compatible)
//  - scoresum/out: A-fragments direct from global (no cross-wave reuse ->
//    LDS staging + per-iter barriers were pure overhead); one barrier total
//  - scoresum phase-2 vectorized (b128 V loads, 8 cols/thread)
// Launches: memset, prep, gemm_qk, scoresum(q), ctxkaeff, scoresum(k), out.
// ---------------------------------------------------------------------------

#define AS1 __attribute__((address_space(1)))
#define AS3 __attribute__((address_space(3)))

typedef __attribute__((ext_vector_type(8))) __bf16   bf16x8;
typedef __attribute__((ext_vector_type(8))) uint16_t u16x8;
typedef __attribute__((ext_vector_type(4))) float    f32x4;

__device__ __forceinline__ float bf2f(uint16_t v) {
  union { uint32_t u; float f; } x; x.u = ((uint32_t)v) << 16; return x.f;
}
__device__ __forceinline__ uint16_t f2bf(float f) {
  uint32_t u = __float_as_uint(f);
  uint32_t r = (u + 0x7fffu + ((u >> 16) & 1u)) >> 16;
  return (uint16_t)r;
}
__device__ __forceinline__ bf16x8 cvt8(const float4 lo, const float4 hi) {
  u16x8 r;
  r[0] = f2bf(lo.x); r[1] = f2bf(lo.y); r[2] = f2bf(lo.z); r[3] = f2bf(lo.w);
  r[4] = f2bf(hi.x); r[5] = f2bf(hi.y); r[6] = f2bf(hi.z); r[7] = f2bf(hi.w);
  union { u16x8 u; bf16x8 b; } c; c.u = r; return c.b;
}
// async global->LDS, 16 B/lane; LDS dest must be lane-contiguous.
__device__ __forceinline__ void gload16(const void* g, void* l) {
  __builtin_amdgcn_global_load_lds((AS1 void*)(void*)g, (AS3 void*)l, 16, 0, 0);
}

// ---------------------------------------------------------------------------
// prep: job0 cvt X->Xb (12288 blocks) | job1 WT=bf16(Wq^T|Wk^T) (4608)
//       | job2 WqaT[hp][k]=bf16(Wqa[k][hp]) (48)
__global__ __launch_bounds__(256) void prep_kernel(
    const float* __restrict__ X, const float* __restrict__ Wq,
    const float* __restrict__ Wk, const float* __restrict__ Wqa,
    uint16_t* __restrict__ Xb, uint16_t* __restrict__ WT,
    uint16_t* __restrict__ WqaT) {
  const int bid = blockIdx.x, tid = threadIdx.x;
  if (bid < 12288) {
    size_t i = ((size_t)bid * 256 + tid) * 8;
    const float* p = X + i;
    *(bf16x8*)(Xb + i) = cvt8(*(const float4*)p, *(const float4*)(p + 4));
  } else if (bid < 16896) {
    int i = (bid - 12288) * 256 + tid;          // 0..1179647
    int j = (i < 589824) ? i : i - 589824;
    const float* src = (i < 589824) ? Wq : Wk;
    int n = j / 768, k = j - n * 768;
    WT[i] = f2bf(src[k * 768 + n]);
  } else {
    int i = (bid - 16896) * 256 + tid;          // 0..12287
    int hp = i / 768, k = i - hp * 768;
    WqaT[i] = (hp < 12) ? f2bf(Wqa[k * 12 + hp]) : (uint16_t)0;
  }
}

// ---------------------------------------------------------------------------
// gemm: C[32768 x 1536] = Xb @ WT^T, bf16 out split Qb/Kb. 128x128 block,
// 4 waves x (64x64), 16x16x32 MFMA, BK=32, DMA staging, XCD swizzle.
// LDS seg-major: slot(seg,row) = seg*128 + row (16B slots) -> conflict-free.
__global__ __launch_bounds__(256) void gemm_qk(
    const uint16_t* __restrict__ Xb, const uint16_t* __restrict__ WT,
    uint16_t* __restrict__ Qb, uint16_t* __restrict__ Kb) {
  __shared__ __align__(16) uint16_t As[128 * 32];
  __shared__ __align__(16) uint16_t Bs[128 * 32];
  const int tid = threadIdx.x;
  const int bid = blockIdx.x;              // 0..3071
  const int xr = bid & 7, th = bid >> 3;   // same-m0 col blocks -> same XCD
  const int nblk = th % 12;
  const int m0 = ((th / 12) * 8 + xr) * 128;
  const uint16_t* BT = WT + (size_t)nblk * 98304;
  uint16_t* C   = (nblk < 6) ? Qb : Kb;
  const int cn0 = ((nblk < 6) ? nblk : nblk - 6) * 128;

  const int wave = tid >> 6, lane = tid & 63, lr = lane & 15, lk = lane >> 4;
  const int wm = (wave & 1) * 64, wn = (wave >> 1) * 64;

  const f32x4 zero = {0.f, 0.f, 0.f, 0.f};
  f32x4 acc[4][4];
#pragma unroll
  for (int mi = 0; mi < 4; mi++)
#pragma unroll
    for (int ni = 0; ni < 4; ni++) acc[mi][ni] = zero;

  const int srow = tid & 127;        // staged row for slots tid / tid+256
  const int sseg = tid >> 7;         // seg 0..1; +2 for second issue

  for (int k0 = 0; k0 < 768; k0 += 32) {
    gload16(Xb + (size_t)(m0 + srow) * 768 + k0 + sseg * 8,        As + tid * 8);
    gload16(Xb + (size_t)(m0 + srow) * 768 + k0 + sseg * 8 + 16,   As + (256 + tid) * 8);
    gload16(BT + (size_t)srow        * 768 + k0 + sseg * 8,        Bs + tid * 8);
    gload16(BT + (size_t)srow        * 768 + k0 + sseg * 8 + 16,   Bs + (256 + tid) * 8);
    __syncthreads();  // drains vmcnt (DMA) before LDS reads
    bf16x8 af[4], bfv[4];
#pragma unroll
    for (int mi = 0; mi < 4; mi++)
      af[mi] = *(const bf16x8*)(As + (lk * 128 + wm + mi * 16 + lr) * 8);
#pragma unroll
    for (int ni = 0; ni < 4; ni++)
      bfv[ni] = *(const bf16x8*)(Bs + (lk * 128 + wn + ni * 16 + lr) * 8);
#pragma unroll
    for (int mi = 0; mi < 4; mi++)
#pragma unroll
      for (int ni = 0; ni < 4; ni++)
        acc[mi][ni] = __builtin_amdgcn_mfma_f32_16x16x32_bf16(
            af[mi], bfv[ni], acc[mi][ni], 0, 0, 0);
    __syncthreads();  // protect LDS from next iteration's DMA
  }
  // C/D layout: col = lane&15, row = (lane>>4)*4 + reg
#pragma unroll
  for (int mi = 0; mi < 4; mi++)
#pragma unroll
    for (int ni = 0; ni < 4; ni++) {
      const int col = cn0 + wn + ni * 16 + lr;
#pragma unroll
      for (int r = 0; r < 4; r++) {
        const int row = m0 + wm + mi * 16 + lk * 4 + r;
        C[(size_t)row * 768 + col] = f2bf(acc[mi][ni][r]);
      }
    }
}

// ---------------------------------------------------------------------------
// scoresum: 64-row block. Phase 1: scores = A @ BT^T (MFMA, N=16), A-frags
// direct from global (no cross-wave reuse), Bs one-time DMA (seg-major:
// slot(seg,h) = seg*16 + h). e = exp(s/8)*mask into LDS.
// Phase 2: 192 threads x (8 cols, 32 rows), b128 V loads; atomics.
__global__ __launch_bounds__(256) void scoresum_kernel(
    const uint16_t* __restrict__ A,      // 32768x768 bf16 (Qb or Kb); also V
    const uint16_t* __restrict__ BT,     // [16][768] bf16 (+bStride per batch)
    const float* __restrict__ mask,
    int bStride,
    float* __restrict__ sumv, float* __restrict__ sume) {
  __shared__ __align__(16) uint16_t Bs[16 * 768];  // 24 KB, seg-major
  __shared__ float eS[64 * 16];                    // 4 KB
  const int tid = threadIdx.x;
  const int m0  = blockIdx.x * 64;
  const int b   = m0 >> 12;
  const uint16_t* BTb = BT + (size_t)b * bStride;
  // fill Bs: slot p = pass*256+tid; seg = p>>4, h = p&15
#pragma unroll
  for (int p = 0; p < 6; p++) {
    const int slot = p * 256 + tid;
    gload16(BTb + (size_t)(slot & 15) * 768 + (slot >> 4) * 8, Bs + slot * 8);
  }
  __syncthreads();  // drains DMA; Bs visible
  const int wave = tid >> 6, lane = tid & 63, lr = lane & 15, lk = lane >> 4;
  const f32x4 zero = {0.f, 0.f, 0.f, 0.f};
  f32x4 acc = zero;
  const uint16_t* Arow = A + (size_t)(m0 + wave * 16 + lr) * 768;
#pragma unroll
  for (int k0 = 0; k0 < 768; k0 += 32) {
    bf16x8 af  = *(const bf16x8*)(Arow + k0 + lk * 8);
    bf16x8 bfv = *(const bf16x8*)(Bs + (((k0 >> 3) + lk) * 16 + lr) * 8);
    acc = __builtin_amdgcn_mfma_f32_16x16x32_bf16(af, bfv, acc, 0, 0, 0);
  }
  // e into LDS: row = wave*16 + lk*4 + r, col(h) = lr
#pragma unroll
  for (int r = 0; r < 4; r++) {
    const int row = wave * 16 + lk * 4 + r;
    eS[row * 16 + lr] = __expf(acc[r] * 0.125f) * mask[m0 + row];
  }
  __syncthreads();
  if (tid < 12) {  // per-h sum of e
    float s = 0.f;
    for (int r = 0; r < 64; r++) s += eS[r * 16 + tid];
    atomicAdd(&sume[b * 12 + tid], s);
  }
  // phase 2: thread t<192: colgroup g = t%96 (8 cols), half = t/96 (32 rows)
  if (tid < 192) {
    const int g = tid % 96, half = tid / 96, h = g >> 3;
    const uint16_t* Vb = A + (size_t)(m0 + half * 32) * 768 + g * 8;
    float a[8] = {0.f, 0.f, 0.f, 0.f, 0.f, 0.f, 0.f, 0.f};
    for (int r = 0; r < 32; r++) {
      const float e = eS[(half * 32 + r) * 16 + h];
      u16x8 v = *(const u16x8*)(Vb + (size_t)r * 768);
#pragma unroll
      for (int j = 0; j < 8; j++) a[j] += e * bf2f(v[j]);
    }
#pragma unroll
    for (int j = 0; j < 8; j++)
      atomicAdd(&sumv[b * 768 + g * 8 + j], a[j]);
  }
}

// ---------------------------------------------------------------------------
// ctxkaeff: qctx = sumeq/(sume+eps); WkaT[b][hp][k] = bf16(qctx*Wka[k][hp])
__global__ __launch_bounds__(256) void ctxkaeff_kernel(
    const float* __restrict__ sumeq, const float* __restrict__ sume,
    const float* __restrict__ Wka, uint16_t* __restrict__ WkaT,
    float* __restrict__ qctx) {
  int i = blockIdx.x * 256 + threadIdx.x;  // 8*16*768
  int k = i % 768, hp = (i / 768) & 15, b = i / 12288;
  float qc = sumeq[b * 768 + k] / (sume[b * 12 + (k >> 6)] + 1e-8f);
  WkaT[i] = (hp < 12) ? f2bf(qc * Wka[k * 12 + hp]) : (uint16_t)0;
  if (hp == 0) qctx[b * 768 + k] = qc;
}

// ---------------------------------------------------------------------------
// out: per (bh, 128-row block): Ms[seg][n] = bf16(kc[d]*Wo[d][n]) seg-major;
// Q-fragments direct from global; out = Q + Qh @ Ms^T (fp32 store).
__global__ __launch_bounds__(256) void out_kernel(
    const uint16_t* __restrict__ Qb,
    const float* __restrict__ qctx, const float* __restrict__ sumv2,
    const float* __restrict__ sume2, const float* __restrict__ Wo,
    float* __restrict__ out) {
  __shared__ __align__(16) uint16_t Ms[64 * 64];   // 8 KB, seg-major
  __shared__ float kcS[64];
  const int tid = threadIdx.x;
  const int bh = blockIdx.x, rb = blockIdx.y;
  const int b = bh / 12, h = bh - b * 12;
  const size_t rowbase = (size_t)b * 4096 + rb * 128;
  const uint16_t* Qh = Qb + rowbase * 768 + h * 64;
  if (tid < 64) {
    const int hd = h * 64 + tid;
    kcS[tid] = qctx[b * 768 + hd] * sumv2[b * 768 + hd] /
               (sume2[b * 12 + h] + 1e-8f);
  }
  __syncthreads();  // kcS ready
  // Ms[(d>>3)*64 + n] elem (d&7) = kc[d]*Wo[d][n]; n fast for coalesced Wo
#pragma unroll
  for (int p = 0; p < 16; p++) {
    const int i = p * 256 + tid;
    const int n = i & 63, d = i >> 6;
    Ms[((d >> 3) * 64 + n) * 8 + (d & 7)] = f2bf(kcS[d] * Wo[d * 64 + n]);
  }
  __syncthreads();  // Ms visible
  const int wave = tid >> 6, lane = tid & 63, lr = lane & 15, lk = lane >> 4;
  const f32x4 zero = {0.f, 0.f, 0.f, 0.f};
  f32x4 acc[2][4];
#pragma unroll
  for (int mi = 0; mi < 2; mi++)
#pragma unroll
    for (int ni = 0; ni < 4; ni++) acc[mi][ni] = zero;
#pragma unroll
  for (int kc = 0; kc < 2; kc++) {
    bf16x8 af[2], bfv[4];
#pragma unroll
    for (int mi = 0; mi < 2; mi++)
      af[mi] = *(const bf16x8*)(Qh + (size_t)(wave * 32 + mi * 16 + lr) * 768 +
                                kc * 32 + lk * 8);
#pragma unroll
    for (int ni = 0; ni < 4; ni++)
      bfv[ni] = *(const bf16x8*)(Ms + ((kc * 4 + lk) * 64 + ni * 16 + lr) * 8);
#pragma unroll
    for (int mi = 0; mi < 2; mi++)
#pragma unroll
      for (int ni = 0; ni < 4; ni++)
        acc[mi][ni] = __builtin_amdgcn_mfma_f32_16x16x32_bf16(
            af[mi], bfv[ni], acc[mi][ni], 0, 0, 0);
  }
#pragma unroll
  for (int mi = 0; mi < 2; mi++)
#pragma unroll
    for (int ni = 0; ni < 4; ni++)
#pragma unroll
      for (int r = 0; r < 4; r++) {
        const int row = wave * 32 + mi * 16 + lk * 4 + r;
        const int col = ni * 16 + lr;
        const float q = bf2f(Qh[(size_t)row * 768 + col]);
        out[(rowbase + row) * 768 + h * 64 + col] = q + acc[mi][ni][r];
      }
}

// ---------------------------------------------------------------------------
extern "C" void kernel_launch(void* const* d_in, const int* in_sizes, int n_in,
                              void* d_out, int out_size, void* d_ws, size_t ws_size,
                              hipStream_t stream) {
  const float* x    = (const float*)d_in[0];
  const float* mask = (const float*)d_in[1];
  const float* Wq   = (const float*)d_in[2];
  const float* Wk   = (const float*)d_in[3];
  const float* Wqa  = (const float*)d_in[4];
  const float* Wka  = (const float*)d_in[5];
  const float* Wo   = (const float*)d_in[6];
  float* out = (float*)d_out;
  char* ws = (char*)d_ws;

  // Xb (bf16 x) lives in d_out's first 50 MB — dead by out_kernel time.
  uint16_t* Xb = (uint16_t*)d_out;

  // workspace layout (bytes)
  uint16_t* Qb    = (uint16_t*)(ws);                    // 50331648
  uint16_t* Kb    = (uint16_t*)(ws + 50331648);         // 50331648
  uint16_t* WT    = (uint16_t*)(ws + 100663296);        // 2359296
  uint16_t* WqaT  = (uint16_t*)(ws + 103022592);        // 24576
  uint16_t* WkaT  = (uint16_t*)(ws + 103047168);        // 196608
  float*    accum = (float*)   (ws + 103243776);        // 49920
  float* sume   = accum;               // 96
  float* sume2  = accum + 96;          // 96
  float* sumeq  = accum + 192;         // 6144
  float* sume2k = accum + 192 + 6144;  // 6144
  float* qctx   = (float*)(ws + 103293696);             // 24576

  hipMemsetAsync(accum, 0, 12480 * sizeof(float), stream);

  prep_kernel<<<16944, 256, 0, stream>>>(x, Wq, Wk, Wqa, Xb, WT, WqaT);
  gemm_qk<<<3072, 256, 0, stream>>>(Xb, WT, Qb, Kb);
  scoresum_kernel<<<512, 256, 0, stream>>>(Qb, WqaT, mask, 0, sumeq, sume);
  ctxkaeff_kernel<<<384, 256, 0, stream>>>(sumeq, sume, Wka, WkaT, qctx);
  scoresum_kernel<<<512, 256, 0, stream>>>(Kb, WkaT, mask, 12288, sume2k, sume2);
  out_kernel<<<dim3(96, 32), 256, 0, stream>>>(Qb, qctx, sume2k, sume2, Wo, out);
}